// Round 3
// baseline (54.379 us; speedup 1.0000x reference)
//
#include <hip/hip_runtime.h>

// PLE encoder: samples (B=8, C=64, L=2048) f32, bin_edges (C, 65) f32 sorted.
// out (B, C*64, L) f32: out[b][c*64+j][l] = 1 if j<bin, (x-left)/w if j==bin, 0 if j>bin
// where bin = #{inner edges <= x}, inner = edges[c][1..63].
//
// Memory-bound: 256 MB streaming write dominates. Each thread handles 4
// consecutive l for one (b,c) -> 64 coalesced float4 stores per thread.
// R3 changes vs R1 (44.9us, 5.8 TB/s):
//   - nontemporal stores via native ext_vector type (HIP_vector_type rejected)
//   - per-block j-rotation to decorrelate the power-of-2-strided write set

#define PLE_B 8
#define PLE_C 64
#define PLE_L 2048
#define PLE_NBINS 64

typedef float f32x4 __attribute__((ext_vector_type(4)));

__global__ __launch_bounds__(256) void ple_kernel(const float* __restrict__ samples,
                                                  const float* __restrict__ edges,
                                                  float* __restrict__ out) {
    __shared__ float se[PLE_NBINS + 1];

    const int bid  = blockIdx.x;
    const int tile = bid & 1;        // 2 tiles of 1024 l-values per (b,c)
    const int bc   = bid >> 1;
    const int c    = bc & (PLE_C - 1);
    const int b    = bc >> 6;        // / PLE_C
    const int tid  = threadIdx.x;

    if (tid < PLE_NBINS + 1) se[tid] = edges[c * (PLE_NBINS + 1) + tid];
    __syncthreads();

    const int l0 = tile * 1024 + tid * 4;
    const f32x4 x = __builtin_nontemporal_load(reinterpret_cast<const f32x4*>(
        samples + ((size_t)b * PLE_C + c) * PLE_L + l0));

    // searchsorted(inner, x, side='right') == count(inner <= x), inner = se[1..63]
    int bin0 = 0, bin1 = 0, bin2 = 0, bin3 = 0;
#pragma unroll
    for (int i = 1; i < PLE_NBINS; ++i) {
        const float e = se[i];           // wave-uniform LDS broadcast
        bin0 += (x.x >= e);
        bin1 += (x.y >= e);
        bin2 += (x.z >= e);
        bin3 += (x.w >= e);
    }

    const float bv0 = (x.x - se[bin0]) / (se[bin0 + 1] - se[bin0]);
    const float bv1 = (x.y - se[bin1]) / (se[bin1 + 1] - se[bin1]);
    const float bv2 = (x.z - se[bin2]) / (se[bin2 + 1] - se[bin2]);
    const float bv3 = (x.w - se[bin3]) / (se[bin3 + 1] - se[bin3]);

    float* outp = out + (((size_t)b * PLE_C + c) * PLE_NBINS) * PLE_L + l0;
    const int rot = bc & (PLE_NBINS - 1);   // decorrelate j-phase across blocks
#pragma unroll
    for (int jj = 0; jj < PLE_NBINS; ++jj) {
        const int j = (jj + rot) & (PLE_NBINS - 1);
        f32x4 v;
        v.x = (j < bin0) ? 1.0f : ((j == bin0) ? bv0 : 0.0f);
        v.y = (j < bin1) ? 1.0f : ((j == bin1) ? bv1 : 0.0f);
        v.z = (j < bin2) ? 1.0f : ((j == bin2) ? bv2 : 0.0f);
        v.w = (j < bin3) ? 1.0f : ((j == bin3) ? bv3 : 0.0f);
        __builtin_nontemporal_store(v, reinterpret_cast<f32x4*>(outp + (size_t)j * PLE_L));
    }
}

extern "C" void kernel_launch(void* const* d_in, const int* in_sizes, int n_in,
                              void* d_out, int out_size, void* d_ws, size_t ws_size,
                              hipStream_t stream) {
    const float* samples = (const float*)d_in[0];
    const float* edges   = (const float*)d_in[1];
    float* out           = (float*)d_out;

    // grid: (B*C) pairs x 2 tiles; block handles 256*4 = 1024 l-values
    const int grid = PLE_B * PLE_C * 2;
    ple_kernel<<<grid, 256, 0, stream>>>(samples, edges, out);
}

// Round 4
// 47.814 us; speedup vs baseline: 1.1373x; 1.1373x over previous
//
#include <hip/hip_runtime.h>

// PLE encoder: samples (B=8, C=64, L=2048) f32, bin_edges (C, 65) f32 sorted.
// out (B, C*64, L) f32: out[b][c*64+j][l] = 1 if j<bin, (x-left)/w if j==bin, 0 if j>bin
// where bin = #{inner edges <= x}, inner = edges[c][1..63].
//
// Memory-bound: 256 MB streaming write dominates.
// R4: revert nt-stores + rotation (R3 regression: L2 write-allocate helps).
//     Grid split over j-halves, not l-halves: each block owns (b,c) x 32 j-rows
//     over the FULL L=2048, so every j-step writes one contiguous 8KB row
//     (vs 4KB strided chunks in R1). 1024 blocks -> 4 blocks/CU.

#define PLE_B 8
#define PLE_C 64
#define PLE_L 2048
#define PLE_NBINS 64

typedef float f32x4 __attribute__((ext_vector_type(4)));

__global__ __launch_bounds__(256) void ple_kernel(const float* __restrict__ samples,
                                                  const float* __restrict__ edges,
                                                  float* __restrict__ out) {
    __shared__ float se[PLE_NBINS + 1];

    const int bid   = blockIdx.x;
    const int jhalf = bid & 1;       // j in [jhalf*32, jhalf*32+32)
    const int bc    = bid >> 1;
    const int c     = bc & (PLE_C - 1);
    const int b     = bc >> 6;       // / PLE_C
    const int tid   = threadIdx.x;

    if (tid < PLE_NBINS + 1) se[tid] = edges[c * (PLE_NBINS + 1) + tid];
    __syncthreads();

    // Each thread owns 8 l-values: [tid*4 .. tid*4+3] and [1024+tid*4 .. +3]
    const float* sp = samples + ((size_t)b * PLE_C + c) * PLE_L + tid * 4;
    const f32x4 xa = *reinterpret_cast<const f32x4*>(sp);
    const f32x4 xb = *reinterpret_cast<const f32x4*>(sp + 1024);

    int bin[8] = {0, 0, 0, 0, 0, 0, 0, 0};
#pragma unroll
    for (int i = 1; i < PLE_NBINS; ++i) {
        const float e = se[i];           // wave-uniform LDS broadcast
        bin[0] += (xa.x >= e);
        bin[1] += (xa.y >= e);
        bin[2] += (xa.z >= e);
        bin[3] += (xa.w >= e);
        bin[4] += (xb.x >= e);
        bin[5] += (xb.y >= e);
        bin[6] += (xb.z >= e);
        bin[7] += (xb.w >= e);
    }

    float bv[8];
    const float xs[8] = {xa.x, xa.y, xa.z, xa.w, xb.x, xb.y, xb.z, xb.w};
#pragma unroll
    for (int k = 0; k < 8; ++k) {
        const float left = se[bin[k]];
        bv[k] = (xs[k] - left) / (se[bin[k] + 1] - left);
    }

    float* outp = out + (((size_t)b * PLE_C + c) * PLE_NBINS + jhalf * 32) * (size_t)PLE_L
                  + tid * 4;
#pragma unroll
    for (int jj = 0; jj < 32; ++jj) {
        const int j = jhalf * 32 + jj;
        f32x4 va, vb;
        va.x = (j < bin[0]) ? 1.0f : ((j == bin[0]) ? bv[0] : 0.0f);
        va.y = (j < bin[1]) ? 1.0f : ((j == bin[1]) ? bv[1] : 0.0f);
        va.z = (j < bin[2]) ? 1.0f : ((j == bin[2]) ? bv[2] : 0.0f);
        va.w = (j < bin[3]) ? 1.0f : ((j == bin[3]) ? bv[3] : 0.0f);
        vb.x = (j < bin[4]) ? 1.0f : ((j == bin[4]) ? bv[4] : 0.0f);
        vb.y = (j < bin[5]) ? 1.0f : ((j == bin[5]) ? bv[5] : 0.0f);
        vb.z = (j < bin[6]) ? 1.0f : ((j == bin[6]) ? bv[6] : 0.0f);
        vb.w = (j < bin[7]) ? 1.0f : ((j == bin[7]) ? bv[7] : 0.0f);
        float* row = outp + (size_t)jj * PLE_L;
        *reinterpret_cast<f32x4*>(row)        = va;
        *reinterpret_cast<f32x4*>(row + 1024) = vb;
    }
}

extern "C" void kernel_launch(void* const* d_in, const int* in_sizes, int n_in,
                              void* d_out, int out_size, void* d_ws, size_t ws_size,
                              hipStream_t stream) {
    const float* samples = (const float*)d_in[0];
    const float* edges   = (const float*)d_in[1];
    float* out           = (float*)d_out;

    // grid: (B*C) pairs x 2 j-halves; each block writes 32 full 8KB rows
    const int grid = PLE_B * PLE_C * 2;
    ple_kernel<<<grid, 256, 0, stream>>>(samples, edges, out);
}

// Round 5
// 45.438 us; speedup vs baseline: 1.1968x; 1.0523x over previous
//
#include <hip/hip_runtime.h>

// PLE encoder: samples (B=8, C=64, L=2048) f32, bin_edges (C, 65) f32 sorted.
// out (B, C*64, L) f32: out[b][c*64+j][l] = 1 if j<bin, (x-left)/w if j==bin, 0 if j>bin
// where bin = #{inner edges <= x}, inner = edges[c][1..63].
//
// Memory-bound: 256 MB streaming write dominates. Plain (cached) stores —
// nt-stores regressed (R3), full-8KB-row blocks regressed (R4).
// R5: R1 store pattern (thread = 4 consecutive l, 4KB chunks / 8KB stride)
//     but grid doubled to 2048 via j-half split -> 8 blocks/CU, 32 waves/CU,
//     half the per-thread j-loop. Tests concurrency/ramp as the limiter.

#define PLE_B 8
#define PLE_C 64
#define PLE_L 2048
#define PLE_NBINS 64

typedef float f32x4 __attribute__((ext_vector_type(4)));

__global__ __launch_bounds__(256) void ple_kernel(const float* __restrict__ samples,
                                                  const float* __restrict__ edges,
                                                  float* __restrict__ out) {
    __shared__ float se[PLE_NBINS + 1];

    const int bid   = blockIdx.x;
    const int jhalf = bid & 1;        // j in [jhalf*32, jhalf*32+32)
    const int tile  = (bid >> 1) & 1; // 2 tiles of 1024 l-values per (b,c)
    const int bc    = bid >> 2;
    const int c     = bc & (PLE_C - 1);
    const int b     = bc >> 6;        // / PLE_C
    const int tid   = threadIdx.x;

    if (tid < PLE_NBINS + 1) se[tid] = edges[c * (PLE_NBINS + 1) + tid];
    __syncthreads();

    const int l0 = tile * 1024 + tid * 4;
    const f32x4 x = *reinterpret_cast<const f32x4*>(
        samples + ((size_t)b * PLE_C + c) * PLE_L + l0);

    // searchsorted(inner, x, side='right') == count(inner <= x), inner = se[1..63]
    int bin0 = 0, bin1 = 0, bin2 = 0, bin3 = 0;
#pragma unroll
    for (int i = 1; i < PLE_NBINS; ++i) {
        const float e = se[i];           // wave-uniform LDS broadcast
        bin0 += (x.x >= e);
        bin1 += (x.y >= e);
        bin2 += (x.z >= e);
        bin3 += (x.w >= e);
    }

    const float bv0 = (x.x - se[bin0]) / (se[bin0 + 1] - se[bin0]);
    const float bv1 = (x.y - se[bin1]) / (se[bin1 + 1] - se[bin1]);
    const float bv2 = (x.z - se[bin2]) / (se[bin2 + 1] - se[bin2]);
    const float bv3 = (x.w - se[bin3]) / (se[bin3 + 1] - se[bin3]);

    float* outp = out + (((size_t)b * PLE_C + c) * PLE_NBINS + jhalf * 32) * (size_t)PLE_L
                  + l0;
#pragma unroll
    for (int jj = 0; jj < 32; ++jj) {
        const int j = jhalf * 32 + jj;
        f32x4 v;
        v.x = (j < bin0) ? 1.0f : ((j == bin0) ? bv0 : 0.0f);
        v.y = (j < bin1) ? 1.0f : ((j == bin1) ? bv1 : 0.0f);
        v.z = (j < bin2) ? 1.0f : ((j == bin2) ? bv2 : 0.0f);
        v.w = (j < bin3) ? 1.0f : ((j == bin3) ? bv3 : 0.0f);
        *reinterpret_cast<f32x4*>(outp + (size_t)jj * PLE_L) = v;
    }
}

extern "C" void kernel_launch(void* const* d_in, const int* in_sizes, int n_in,
                              void* d_out, int out_size, void* d_ws, size_t ws_size,
                              hipStream_t stream) {
    const float* samples = (const float*)d_in[0];
    const float* edges   = (const float*)d_in[1];
    float* out           = (float*)d_out;

    // grid: (B*C) x 2 l-tiles x 2 j-halves = 2048 blocks, 8 blocks/CU
    const int grid = PLE_B * PLE_C * 2 * 2;
    ple_kernel<<<grid, 256, 0, stream>>>(samples, edges, out);
}

// Round 6
// 45.246 us; speedup vs baseline: 1.2019x; 1.0043x over previous
//
#include <hip/hip_runtime.h>

// PLE encoder: samples (B=8, C=64, L=2048) f32, bin_edges (C, 65) f32 sorted.
// out (B, C*64, L) f32: out[b][c*64+j][l] = 1 if j<bin, (x-left)/w if j==bin, 0 if j>bin
// where bin = #{inner edges <= x}, inner = edges[c][1..63].
//
// FINAL (= R1, best of 5 variants at 44.9us = 5.8 TB/s effective):
//   - thread owns 4 consecutive l for one (b,c): 64 coalesced float4 stores
//   - plain cached stores (nt-stores regressed 20%: L2 write-allocate helps)
//   - 1024 blocks (4/CU); j-split (R5) and full-row blocks (R4) were neutral/worse
// Roofline: 256MB write + 4MB read; fill-kernel ceiling ~7.0 TB/s => ~37us
// + ~3-5us launch/ramp => ~41-44us practical floor. We sit within a few %.

#define PLE_B 8
#define PLE_C 64
#define PLE_L 2048
#define PLE_NBINS 64

typedef float f32x4 __attribute__((ext_vector_type(4)));

__global__ __launch_bounds__(256) void ple_kernel(const float* __restrict__ samples,
                                                  const float* __restrict__ edges,
                                                  float* __restrict__ out) {
    __shared__ float se[PLE_NBINS + 1];

    const int bid  = blockIdx.x;
    const int tile = bid & 1;        // 2 tiles of 1024 l-values per (b,c)
    const int bc   = bid >> 1;
    const int c    = bc & (PLE_C - 1);
    const int b    = bc >> 6;        // / PLE_C
    const int tid  = threadIdx.x;

    if (tid < PLE_NBINS + 1) se[tid] = edges[c * (PLE_NBINS + 1) + tid];
    __syncthreads();

    const int l0 = tile * 1024 + tid * 4;
    const f32x4 x = *reinterpret_cast<const f32x4*>(
        samples + ((size_t)b * PLE_C + c) * PLE_L + l0);

    // searchsorted(inner, x, side='right') == count(inner <= x), inner = se[1..63]
    int bin0 = 0, bin1 = 0, bin2 = 0, bin3 = 0;
#pragma unroll
    for (int i = 1; i < PLE_NBINS; ++i) {
        const float e = se[i];           // wave-uniform LDS broadcast
        bin0 += (x.x >= e);
        bin1 += (x.y >= e);
        bin2 += (x.z >= e);
        bin3 += (x.w >= e);
    }

    const float bv0 = (x.x - se[bin0]) / (se[bin0 + 1] - se[bin0]);
    const float bv1 = (x.y - se[bin1]) / (se[bin1 + 1] - se[bin1]);
    const float bv2 = (x.z - se[bin2]) / (se[bin2 + 1] - se[bin2]);
    const float bv3 = (x.w - se[bin3]) / (se[bin3 + 1] - se[bin3]);

    float* outp = out + (((size_t)b * PLE_C + c) * PLE_NBINS) * (size_t)PLE_L + l0;
#pragma unroll
    for (int j = 0; j < PLE_NBINS; ++j) {
        f32x4 v;
        v.x = (j < bin0) ? 1.0f : ((j == bin0) ? bv0 : 0.0f);
        v.y = (j < bin1) ? 1.0f : ((j == bin1) ? bv1 : 0.0f);
        v.z = (j < bin2) ? 1.0f : ((j == bin2) ? bv2 : 0.0f);
        v.w = (j < bin3) ? 1.0f : ((j == bin3) ? bv3 : 0.0f);
        *reinterpret_cast<f32x4*>(outp + (size_t)j * PLE_L) = v;
    }
}

extern "C" void kernel_launch(void* const* d_in, const int* in_sizes, int n_in,
                              void* d_out, int out_size, void* d_ws, size_t ws_size,
                              hipStream_t stream) {
    const float* samples = (const float*)d_in[0];
    const float* edges   = (const float*)d_in[1];
    float* out           = (float*)d_out;

    // grid: (B*C) pairs x 2 l-tiles; block handles 256*4 = 1024 l-values
    const int grid = PLE_B * PLE_C * 2;
    ple_kernel<<<grid, 256, 0, stream>>>(samples, edges, out);
}